// Round 1
// baseline (510.019 us; speedup 1.0000x reference)
//
#include <hip/hip_runtime.h>
#include <math.h>

typedef __bf16 bf16_t;
typedef bf16_t bf16x8 __attribute__((ext_vector_type(8)));
typedef float  f32x4  __attribute__((ext_vector_type(8/2)));

#define B_SZ   16384
#define H_SZ   50
#define D_SZ   128
#define NI_SZ  100000
#define SCALE  0.08838834764831845f   /* 1/sqrt(128) */

// ---------------------------------------------------------------------------
// C = relu(A[aidx?] @ W + bias), K = N = 128.  Block: 256 thr = 4 waves,
// 64 rows/block tile, grid-stride over row tiles.  W staged in LDS as
// transposed hi/lo bf16 with XOR-swizzled 16B granules; per-(kk,l4) frag is
// one ds_read_b128.  3-term split-bf16 MFMA (hh + lh + hl) ~= fp32 accuracy.
// k-map used for BOTH A and B frags: k = kk*32 + 16*(e>>2) + 4*(lane>>4) + (e&3)
// (any consistent bijection is valid).  C/D layout: col=lane&15,
// row=(lane>>4)*4+reg  [HW-measured].
// ---------------------------------------------------------------------------
template<bool GATHER, bool OUTBF16>
__global__ __launch_bounds__(256, 2)
void gemm128(const float* __restrict__ A, const int* __restrict__ aidx, int M,
             const float* __restrict__ W, const float* __restrict__ bias,
             void* __restrict__ Cout)
{
    __shared__ bf16_t Whi[128 * 128];
    __shared__ bf16_t Wlo[128 * 128];
    const int t = threadIdx.x;

    // ---- stage W (element W[k][n] -> Wt[n][perm(k)]) ----
    for (int i = 0; i < 64; ++i) {
        int flat = t + i * 256;            // coalesced
        int k = flat >> 7, n = flat & 127;
        float w = W[flat];
        bf16_t hi = (bf16_t)w;
        bf16_t lo = (bf16_t)(w - (float)hi);
        int k32 = k & 31, kk = k >> 5;
        int g   = (k32 >> 2) & 3;
        int pos = (k32 & 3) + ((k32 >> 4) & 1) * 4;
        int gidx = (kk * 4 + g) ^ (n & 7);           // bank swizzle
        int off  = n * 128 + gidx * 8 + pos;
        Whi[off] = hi;
        Wlo[off] = lo;
    }
    __syncthreads();

    const int wave = t >> 6, lane = t & 63;
    const int l15 = lane & 15, l4 = lane >> 4;

    float bv[8];
#pragma unroll
    for (int n = 0; n < 8; ++n) bv[n] = bias[n * 16 + l15];

    const int numTiles = (M + 63) >> 6;
    for (int tile = blockIdx.x; tile < numTiles; tile += gridDim.x) {
        const int row0 = tile * 64 + wave * 16;
        int arow = row0 + l15;
        int arc  = arow < M ? arow : M - 1;
        long src = GATHER ? (long)aidx[arc] : (long)arc;
        const float* Ar = A + src * 128;

        f32x4 acc[8];
#pragma unroll
        for (int n = 0; n < 8; ++n) acc[n] = (f32x4){0.f, 0.f, 0.f, 0.f};

#pragma unroll
        for (int kk = 0; kk < 4; ++kk) {
            const f32x4 a0 = *(const f32x4*)(Ar + kk * 32 + 4 * l4);
            const f32x4 a1 = *(const f32x4*)(Ar + kk * 32 + 16 + 4 * l4);
            bf16x8 ahi, alo;
#pragma unroll
            for (int e = 0; e < 4; ++e) {
                bf16_t h0 = (bf16_t)a0[e];
                ahi[e] = h0;
                alo[e] = (bf16_t)(a0[e] - (float)h0);
                bf16_t h1 = (bf16_t)a1[e];
                ahi[4 + e] = h1;
                alo[4 + e] = (bf16_t)(a1[e] - (float)h1);
            }
#pragma unroll
            for (int n = 0; n < 8; ++n) {
                int ncol = n * 16 + l15;
                int off  = ncol * 128 + (((kk * 4 + l4) ^ (ncol & 7)) * 8);
                bf16x8 bhi = *(const bf16x8*)(Whi + off);
                bf16x8 blo = *(const bf16x8*)(Wlo + off);
                acc[n] = __builtin_amdgcn_mfma_f32_16x16x32_bf16(ahi, bhi, acc[n], 0, 0, 0);
                acc[n] = __builtin_amdgcn_mfma_f32_16x16x32_bf16(alo, bhi, acc[n], 0, 0, 0);
                acc[n] = __builtin_amdgcn_mfma_f32_16x16x32_bf16(ahi, blo, acc[n], 0, 0, 0);
            }
        }
#pragma unroll
        for (int n = 0; n < 8; ++n) {
            int col = n * 16 + l15;
#pragma unroll
            for (int r = 0; r < 4; ++r) {
                int row = row0 + l4 * 4 + r;
                if (row < M) {
                    float v = acc[n][r] + bv[n];
                    v = v > 0.f ? v : 0.f;
                    if (OUTBF16)
                        ((bf16_t*)Cout)[(size_t)row * 128 + col] = (bf16_t)v;
                    else
                        ((float*)Cout)[(size_t)row * 128 + col] = v;
                }
            }
        }
    }
}

// ---------------------------------------------------------------------------
// GAT attention: one wave per batch row.  Scores: lane h streams kt[row_h]
// (256B/lane).  Wave softmax over 50 lanes.  V pass: coalesced 4B/lane reads
// of vt rows with broadcast p_h.
// ---------------------------------------------------------------------------
__global__ __launch_bounds__(256)
void gat_attn(const float* __restrict__ qg, const bf16_t* __restrict__ kt,
              const bf16_t* __restrict__ vt, const int* __restrict__ um,
              float* __restrict__ y)
{
    __shared__ float qsh[4][128];
    const int wave = threadIdx.x >> 6, lane = threadIdx.x & 63;
    const int b = blockIdx.x * 4 + wave;

    float2 q2 = *(const float2*)(qg + (size_t)b * 128 + lane * 2);
    qsh[wave][lane * 2]     = q2.x;
    qsh[wave][lane * 2 + 1] = q2.y;
    __syncthreads();

    int   mrow = 0;
    float s = -1e30f;
    if (lane < H_SZ) {
        mrow = um[((size_t)b * H_SZ + lane) * 2];
        const bf16_t* kr = kt + (size_t)mrow * 128;
        float acc = 0.f;
#pragma unroll
        for (int j = 0; j < 16; ++j) {
            bf16x8 kc = *(const bf16x8*)(kr + j * 8);
#pragma unroll
            for (int e = 0; e < 8; ++e) acc += (float)kc[e] * qsh[wave][j * 8 + e];
        }
        s = acc * SCALE;
    }
    float m = s;
#pragma unroll
    for (int off = 32; off; off >>= 1) m = fmaxf(m, __shfl_xor(m, off));
    float p = (lane < H_SZ) ? __expf(s - m) : 0.f;
    float sum = p;
#pragma unroll
    for (int off = 32; off; off >>= 1) sum += __shfl_xor(sum, off);
    p /= sum;

    float ax = 0.f, ay = 0.f;
    for (int h = 0; h < H_SZ; ++h) {
        float ph = __shfl(p, h);
        int   vr = __shfl(mrow, h);
        unsigned u = *(const unsigned*)(vt + (size_t)vr * 128 + lane * 2);
        float v0 = __uint_as_float(u << 16);
        float v1 = __uint_as_float(u & 0xffff0000u);
        ax += ph * v0;
        ay += ph * v1;
    }
    float2 o; o.x = ax; o.y = ay;
    *(float2*)(y + (size_t)b * 128 + lane * 2) = o;
}

// ---------------------------------------------------------------------------
// Semantic attention (2 keys): one wave per batch row, lane owns dims 2l,2l+1.
// ---------------------------------------------------------------------------
__global__ __launch_bounds__(256)
void sem_attn(const float* __restrict__ qs, const float* __restrict__ k1,
              const float* __restrict__ v1, const float* __restrict__ k2,
              const float* __restrict__ v2, float* __restrict__ out)
{
    const int wave = threadIdx.x >> 6, lane = threadIdx.x & 63;
    const size_t base = ((size_t)(blockIdx.x * 4 + wave)) * 128 + lane * 2;
    float2 q  = *(const float2*)(qs + base);
    float2 a1 = *(const float2*)(k1 + base);
    float2 a2 = *(const float2*)(k2 + base);
    float d1 = q.x * a1.x + q.y * a1.y;
    float d2 = q.x * a2.x + q.y * a2.y;
#pragma unroll
    for (int off = 32; off; off >>= 1) {
        d1 += __shfl_xor(d1, off);
        d2 += __shfl_xor(d2, off);
    }
    float s1 = d1 * SCALE, s2 = d2 * SCALE;
    float m = fmaxf(s1, s2);
    float e1 = __expf(s1 - m), e2 = __expf(s2 - m);
    float inv = 1.f / (e1 + e2);
    float p1 = e1 * inv, p2 = e2 * inv;
    float2 b1 = *(const float2*)(v1 + base);
    float2 b2 = *(const float2*)(v2 + base);
    float2 o;
    o.x = p1 * b1.x + p2 * b2.x;
    o.y = p1 * b1.y + p2 * b2.y;
    *(float2*)(out + base) = o;
}

// ---------------------------------------------------------------------------
extern "C" void kernel_launch(void* const* d_in, const int* in_sizes, int n_in,
                              void* d_out, int out_size, void* d_ws, size_t ws_size,
                              hipStream_t stream)
{
    const int*   uids       = (const int*)d_in[0];
    const int*   um         = (const int*)d_in[2];
    const float* user_table = (const float*)d_in[3];
    const float* item_table = (const float*)d_in[5];
    const float* gwq = (const float*)d_in[6];  const float* gbq = (const float*)d_in[7];
    const float* gwk = (const float*)d_in[8];  const float* gbk = (const float*)d_in[9];
    const float* gwv = (const float*)d_in[10]; const float* gbv = (const float*)d_in[11];
    const float* gwo = (const float*)d_in[12]; const float* gbo = (const float*)d_in[13];
    const float* swq = (const float*)d_in[14]; const float* sbq = (const float*)d_in[15];
    const float* swk = (const float*)d_in[16]; const float* sbk = (const float*)d_in[17];
    const float* swv = (const float*)d_in[18]; const float* sbv = (const float*)d_in[19];
    const float* swo = (const float*)d_in[20]; const float* sbo = (const float*)d_in[21];

    char* ws = (char*)d_ws;
    bf16_t* kt  = (bf16_t*)ws; ws += (size_t)NI_SZ * 128 * 2;
    bf16_t* vt  = (bf16_t*)ws; ws += (size_t)NI_SZ * 128 * 2;
    float*  qg  = (float*)ws;  ws += (size_t)B_SZ * 128 * 4;   // reused as qs
    float*  yb  = (float*)ws;  ws += (size_t)B_SZ * 128 * 4;   // reused as k2
    float*  agg = (float*)ws;  ws += (size_t)B_SZ * 128 * 4;
    float*  k1  = (float*)ws;  ws += (size_t)B_SZ * 128 * 4;
    float*  v1  = (float*)ws;  ws += (size_t)B_SZ * 128 * 4;
    float*  v2  = (float*)ws;  ws += (size_t)B_SZ * 128 * 4;
    float*  outf = (float*)d_out;

    dim3 blk(256);

    // GAT stage
    gemm128<true,  false><<<256, blk, 0, stream>>>(user_table, uids, B_SZ, gwq, gbq, qg);
    gemm128<false, true ><<<512, blk, 0, stream>>>(item_table, nullptr, NI_SZ, gwk, gbk, kt);
    gemm128<false, true ><<<512, blk, 0, stream>>>(item_table, nullptr, NI_SZ, gwv, gbv, vt);
    gat_attn<<<B_SZ / 4, blk, 0, stream>>>(qg, kt, vt, um, yb);
    gemm128<false, false><<<256, blk, 0, stream>>>(yb, nullptr, B_SZ, gwo, gbo, agg);

    // SEM projections (qg reused as qs only after gat_attn consumed it)
    gemm128<true,  false><<<256, blk, 0, stream>>>(user_table, uids, B_SZ, swq, sbq, qg);
    gemm128<true,  false><<<256, blk, 0, stream>>>(user_table, uids, B_SZ, swk, sbk, k1);
    gemm128<true,  false><<<256, blk, 0, stream>>>(user_table, uids, B_SZ, swv, sbv, v1);
    gemm128<false, false><<<256, blk, 0, stream>>>(agg, nullptr, B_SZ, swk, sbk, yb);   // k2
    gemm128<false, false><<<256, blk, 0, stream>>>(agg, nullptr, B_SZ, swv, sbv, v2);

    // SEM attention -> ys (in d_out), then in-place output projection.
    // In-place is safe: each wave's C rows == its A rows, and every lane's
    // stores depend (through MFMA cross-lane dataflow) on all A loads.
    sem_attn<<<B_SZ / 4, blk, 0, stream>>>(qg, k1, v1, yb, v2, outf);
    gemm128<false, false><<<256, blk, 0, stream>>>(outf, nullptr, B_SZ, swo, sbo, outf);
}

// Round 2
// 477.633 us; speedup vs baseline: 1.0678x; 1.0678x over previous
//
#include <hip/hip_runtime.h>
#include <math.h>

typedef __bf16 bf16_t;
typedef bf16_t bf16x8 __attribute__((ext_vector_type(8)));
typedef float  f32x4  __attribute__((ext_vector_type(4)));
typedef unsigned short u16;

#define B_SZ   16384
#define H_SZ   50
#define NI_SZ  100000
#define SCALE  0.08838834764831845f   /* 1/sqrt(128) */
#define FRAG_W 32768                  /* u16 elems per W (hi+lo, 2x16384) */

// Logical-k bijection used consistently for A and B fragments of
// mfma_f32_16x16x32_bf16:  k = kk*32 + 16*(e>>2) + 4*l4 + (e&3).
// C/D layout (HW): col = lane&15, row = (lane>>4)*4 + reg.

// ---------------------------------------------------------------------------
// Prep: W[k][n] (f32, 128x128) -> frag-ready hi/lo bf16 arrays.
// dst[w][t][ ((kk*8+nblk)*64 + lane)*8 + e ]  so a wave's (kk,n) B-frag read
// is 1024 contiguous bytes.
// ---------------------------------------------------------------------------
struct WPtrs { const float* p[8]; };

__global__ void prep_frags(WPtrs wp, u16* __restrict__ dst)
{
    int tid = blockIdx.x * 256 + threadIdx.x;      // 8 * 16384 threads
    int w = tid >> 14, idx = tid & 16383;
    int k = idx >> 7, n = idx & 127;
    float v = wp.p[w][idx];
    bf16_t hi = (bf16_t)v;
    bf16_t lo = (bf16_t)(v - (float)hi);
    int kk = k >> 5, k32 = k & 31;
    int e  = ((k32 >> 4) & 1) * 4 + (k32 & 3);
    int l4 = (k32 >> 2) & 3;
    int lane = l4 * 16 + (n & 15);
    int pos = ((kk * 8 + (n >> 4)) * 64 + lane) * 8 + e;
    union { bf16_t b; u16 u; } ch, cl; ch.b = hi; cl.b = lo;
    dst[(size_t)w * FRAG_W + pos]         = ch.u;
    dst[(size_t)w * FRAG_W + 16384 + pos] = cl.u;
}

// ---------------------------------------------------------------------------
// Generic fused GEMM: out_w = relu(A[aidx?] @ W_w + b_w) for w in [0,NW).
// K=N=128.  Block 256 = 4 waves; wave owns 16*RG rows; B-frags read from
// prepped global arrays (L2-resident), TERMS = 1 (bf16) or 3 (split fp32-ish).
// ---------------------------------------------------------------------------
template<int NW, int TERMS, bool GATHER, bool OUTBF16, int RG>
__global__ __launch_bounds__(256)
void gemmN(const float* __restrict__ A, const int* __restrict__ aidx, int M,
           const u16* __restrict__ frags, int4 widx,
           const float* b0, const float* b1, const float* b2, const float* b3,
           char* o0, char* o1, char* o2, char* o3, int rowStride)
{
    __shared__ u16 bounce[OUTBF16 ? 4 * 16 * 136 : 4];
    const int t = threadIdx.x, wave = t >> 6, lane = t & 63;
    const int l15 = lane & 15, l4 = lane >> 4;
    const float* biases[4] = {b0, b1, b2, b3};
    char* outs[4] = {o0, o1, o2, o3};
    const int wsel[4] = {widx.x, widx.y, widx.z, widx.w};

    float bv[NW][8];
#pragma unroll
    for (int w = 0; w < NW; ++w)
#pragma unroll
        for (int n = 0; n < 8; ++n) bv[w][n] = biases[w][n * 16 + l15];

    const int rowsPerBlock = 64 * RG;
    const int numTiles = (M + rowsPerBlock - 1) / rowsPerBlock;

    for (int tile = blockIdx.x; tile < numTiles; tile += gridDim.x) {
        const int rbase = tile * rowsPerBlock + wave * (16 * RG);

        // ---- A load + repack to bf16 frags (hi, and lo residual if TERMS>1)
        bf16x8 ahi[RG][4], alo[RG][4];
#pragma unroll
        for (int rg = 0; rg < RG; ++rg) {
            int arow = rbase + rg * 16 + l15;
            int arc  = arow < M ? arow : M - 1;
            long src = GATHER ? (long)aidx[arc] : (long)arc;
            const float* Ar = A + src * 128;
#pragma unroll
            for (int kk = 0; kk < 4; ++kk) {
                f32x4 a0 = *(const f32x4*)(Ar + kk * 32 + 4 * l4);
                f32x4 a1 = *(const f32x4*)(Ar + kk * 32 + 16 + 4 * l4);
#pragma unroll
                for (int e = 0; e < 4; ++e) {
                    bf16_t h0 = (bf16_t)a0[e];
                    ahi[rg][kk][e] = h0;
                    if (TERMS > 1) alo[rg][kk][e] = (bf16_t)(a0[e] - (float)h0);
                    bf16_t h1 = (bf16_t)a1[e];
                    ahi[rg][kk][4 + e] = h1;
                    if (TERMS > 1) alo[rg][kk][4 + e] = (bf16_t)(a1[e] - (float)h1);
                }
            }
        }

#pragma unroll
        for (int w = 0; w < NW; ++w) {
            const u16* fh = frags + (size_t)wsel[w] * FRAG_W;
            const u16* fl = fh + 16384;
            f32x4 acc[RG][8];
#pragma unroll
            for (int rg = 0; rg < RG; ++rg)
#pragma unroll
                for (int n = 0; n < 8; ++n) acc[rg][n] = (f32x4){0.f, 0.f, 0.f, 0.f};

#pragma unroll
            for (int kk = 0; kk < 4; ++kk)
#pragma unroll
                for (int n = 0; n < 8; ++n) {
                    int foff = ((kk * 8 + n) * 64 + lane) * 8;
                    bf16x8 bhi = *(const bf16x8*)(fh + foff);
#pragma unroll
                    for (int rg = 0; rg < RG; ++rg)
                        acc[rg][n] = __builtin_amdgcn_mfma_f32_16x16x32_bf16(ahi[rg][kk], bhi, acc[rg][n], 0, 0, 0);
                    if (TERMS > 1) {
#pragma unroll
                        for (int rg = 0; rg < RG; ++rg)
                            acc[rg][n] = __builtin_amdgcn_mfma_f32_16x16x32_bf16(alo[rg][kk], bhi, acc[rg][n], 0, 0, 0);
                    }
                    if (TERMS > 2) {
                        bf16x8 blo = *(const bf16x8*)(fl + foff);
#pragma unroll
                        for (int rg = 0; rg < RG; ++rg)
                            acc[rg][n] = __builtin_amdgcn_mfma_f32_16x16x32_bf16(ahi[rg][kk], blo, acc[rg][n], 0, 0, 0);
                    }
                }

            // ---- epilogue
#pragma unroll
            for (int rg = 0; rg < RG; ++rg) {
                int row0 = rbase + rg * 16;
                if (row0 >= M) continue;              // M % 16 == 0 always here
                if (OUTBF16) {
                    u16* bb = (u16*)bounce + wave * (16 * 136);
#pragma unroll
                    for (int n = 0; n < 8; ++n)
#pragma unroll
                        for (int r = 0; r < 4; ++r) {
                            float v = acc[rg][n][r] + bv[w][n];
                            v = v > 0.f ? v : 0.f;
                            union { bf16_t b; u16 u; } c; c.b = (bf16_t)v;
                            bb[(l4 * 4 + r) * 136 + n * 16 + l15] = c.u;
                        }
                    __asm__ volatile("s_waitcnt lgkmcnt(0)" ::: "memory");
                    int rl = lane >> 2, c0 = (lane & 3) * 32;
                    char* ob = outs[w] + ((size_t)(row0 + rl) * rowStride + c0) * 2;
                    const u16* sp = bb + rl * 136 + c0;
#pragma unroll
                    for (int j = 0; j < 4; ++j)
                        *(ulonglong2*)(ob + j * 16) = *(const ulonglong2*)(sp + j * 8);
                } else {
#pragma unroll
                    for (int n = 0; n < 8; ++n)
#pragma unroll
                        for (int r = 0; r < 4; ++r) {
                            float v = acc[rg][n][r] + bv[w][n];
                            v = v > 0.f ? v : 0.f;
                            *(float*)(outs[w] + ((size_t)(row0 + l4 * 4 + r) * rowStride + n * 16 + l15) * 4) = v;
                        }
                }
            }
        }
    }
}

// ---------------------------------------------------------------------------
// GAT attention, single gather pass.  kv[item] = [k 128 bf16 | v 128 bf16].
// Wave per batch row: V rows preloaded into 50 regs (coalesced 4B/lane),
// K streamed per-lane (lane h owns key h), wave softmax, in-register PV.
// ---------------------------------------------------------------------------
__global__ __launch_bounds__(256)
void gat_attn(const float* __restrict__ qg, const u16* __restrict__ kv,
              const int* __restrict__ um, float* __restrict__ y)
{
    __shared__ float qsh[4][128];
    const int wave = threadIdx.x >> 6, lane = threadIdx.x & 63;
    const int b = blockIdx.x * 4 + wave;

    float2 q2 = *(const float2*)(qg + (size_t)b * 128 + lane * 2);
    qsh[wave][lane * 2]     = q2.x;
    qsh[wave][lane * 2 + 1] = q2.y;

    int mrow = (lane < H_SZ) ? um[((size_t)b * H_SZ + lane) * 2] : 0;

    // V preload: 50 coalesced wave-reads, 1 u32 (2 bf16 dims) per lane each.
    unsigned vreg[H_SZ];
#pragma unroll
    for (int h = 0; h < H_SZ; ++h) {
        int vr = __shfl(mrow, h);
        vreg[h] = *(const unsigned*)(kv + (size_t)vr * 256 + 128 + lane * 2);
    }
    __syncthreads();

    // Scores: lane h streams key row h (256 B) in 4 chunks.
    float s = -1e30f;
    if (lane < H_SZ) {
        const u16* kr = kv + (size_t)mrow * 256;
        float acc = 0.f;
#pragma unroll
        for (int c = 0; c < 4; ++c) {
            bf16x8 kc[4];
#pragma unroll
            for (int j = 0; j < 4; ++j) kc[j] = *(const bf16x8*)(kr + (c * 4 + j) * 8);
#pragma unroll
            for (int j = 0; j < 4; ++j)
#pragma unroll
                for (int e = 0; e < 8; ++e)
                    acc += (float)kc[j][e] * qsh[wave][(c * 4 + j) * 8 + e];
        }
        s = acc * SCALE;
    }
    float m = s;
#pragma unroll
    for (int off = 32; off; off >>= 1) m = fmaxf(m, __shfl_xor(m, off));
    float p = (lane < H_SZ) ? __expf(s - m) : 0.f;
    float sum = p;
#pragma unroll
    for (int off = 32; off; off >>= 1) sum += __shfl_xor(sum, off);
    p /= sum;

    float ax = 0.f, ay = 0.f;
#pragma unroll
    for (int h = 0; h < H_SZ; ++h) {
        float ph = __shfl(p, h);
        unsigned u = vreg[h];
        ax += ph * __uint_as_float(u << 16);
        ay += ph * __uint_as_float(u & 0xffff0000u);
    }
    *(float2*)(y + (size_t)b * 128 + lane * 2) = (float2){ax, ay};
}

// ---------------------------------------------------------------------------
// Semantic attention (2 keys): wave per row, lane owns dims 2l, 2l+1.
// ---------------------------------------------------------------------------
__global__ __launch_bounds__(256)
void sem_attn(const float* __restrict__ qs, const float* __restrict__ k1,
              const float* __restrict__ v1, const float* __restrict__ k2,
              const float* __restrict__ v2, float* __restrict__ out)
{
    const int wave = threadIdx.x >> 6, lane = threadIdx.x & 63;
    const size_t base = ((size_t)(blockIdx.x * 4 + wave)) * 128 + lane * 2;
    float2 q  = *(const float2*)(qs + base);
    float2 a1 = *(const float2*)(k1 + base);
    float2 a2 = *(const float2*)(k2 + base);
    float d1 = q.x * a1.x + q.y * a1.y;
    float d2 = q.x * a2.x + q.y * a2.y;
#pragma unroll
    for (int off = 32; off; off >>= 1) {
        d1 += __shfl_xor(d1, off);
        d2 += __shfl_xor(d2, off);
    }
    float s1 = d1 * SCALE, s2 = d2 * SCALE;
    float m = fmaxf(s1, s2);
    float e1 = __expf(s1 - m), e2 = __expf(s2 - m);
    float inv = 1.f / (e1 + e2);
    float p1 = e1 * inv, p2 = e2 * inv;
    float2 b1 = *(const float2*)(v1 + base);
    float2 b2 = *(const float2*)(v2 + base);
    *(float2*)(out + base) = (float2){p1 * b1.x + p2 * b2.x, p1 * b1.y + p2 * b2.y};
}

// ---------------------------------------------------------------------------
extern "C" void kernel_launch(void* const* d_in, const int* in_sizes, int n_in,
                              void* d_out, int out_size, void* d_ws, size_t ws_size,
                              hipStream_t stream)
{
    const int*   uids       = (const int*)d_in[0];
    const int*   um         = (const int*)d_in[2];
    const float* user_table = (const float*)d_in[3];
    const float* item_table = (const float*)d_in[5];
    const float* gwq = (const float*)d_in[6];  const float* gbq = (const float*)d_in[7];
    const float* gwk = (const float*)d_in[8];  const float* gbk = (const float*)d_in[9];
    const float* gwv = (const float*)d_in[10]; const float* gbv = (const float*)d_in[11];
    const float* gwo = (const float*)d_in[12]; const float* gbo = (const float*)d_in[13];
    const float* swq = (const float*)d_in[14]; const float* sbq = (const float*)d_in[15];
    const float* swk = (const float*)d_in[16]; const float* sbk = (const float*)d_in[17];
    const float* swv = (const float*)d_in[18]; const float* sbv = (const float*)d_in[19];
    const float* swo = (const float*)d_in[20]; const float* sbo = (const float*)d_in[21];

    char* ws = (char*)d_ws;
    u16*   kv    = (u16*)ws;   ws += (size_t)NI_SZ * 256 * 2;     // 51.2 MB
    u16*   frags = (u16*)ws;   ws += (size_t)8 * FRAG_W * 2;      // 0.5 MB
    float* qg  = (float*)ws;   ws += (size_t)B_SZ * 128 * 4;
    float* qs  = (float*)ws;   ws += (size_t)B_SZ * 128 * 4;
    float* k1  = (float*)ws;   ws += (size_t)B_SZ * 128 * 4;
    float* v1  = (float*)ws;   ws += (size_t)B_SZ * 128 * 4;
    float* yb  = (float*)ws;   ws += (size_t)B_SZ * 128 * 4;
    float* agg = (float*)ws;   ws += (size_t)B_SZ * 128 * 4;
    // k2/v2 live in the kv region (kv is dead after gat_attn)
    float* k2 = (float*)kv;
    float* v2 = (float*)((char*)kv + (size_t)B_SZ * 128 * 4);
    float* outf = (float*)d_out;

    // W order: 0 gwq, 1 gwk, 2 gwv, 3 gwo, 4 swq, 5 swk, 6 swv, 7 swo
    WPtrs wp; wp.p[0]=gwq; wp.p[1]=gwk; wp.p[2]=gwv; wp.p[3]=gwo;
              wp.p[4]=swq; wp.p[5]=swk; wp.p[6]=swv; wp.p[7]=swo;
    prep_frags<<<512, 256, 0, stream>>>(wp, frags);

    // Item K+V (fused, bf16, kv-interleaved rows of 256 elems)
    gemmN<2, 1, false, true, 2><<<512, 256, 0, stream>>>(
        item_table, nullptr, NI_SZ, frags, (int4){1, 2, 0, 0},
        gbk, gbv, nullptr, nullptr,
        (char*)kv, (char*)(kv + 128), nullptr, nullptr, 256);

    // Node projections (fused 4): gat_q, sem_q, sem_k1, sem_v1
    gemmN<4, 3, true, false, 1><<<256, 256, 0, stream>>>(
        user_table, uids, B_SZ, frags, (int4){0, 4, 5, 6},
        gbq, sbq, sbk, sbv,
        (char*)qg, (char*)qs, (char*)k1, (char*)v1, 128);

    gat_attn<<<B_SZ / 4, 256, 0, stream>>>(qg, kv, um, yb);

    // agg = relu(yb @ gwo + gbo)
    gemmN<1, 3, false, false, 1><<<256, 256, 0, stream>>>(
        yb, nullptr, B_SZ, frags, (int4){3, 0, 0, 0},
        gbo, nullptr, nullptr, nullptr,
        (char*)agg, nullptr, nullptr, nullptr, 128);

    // k2, v2 = relu(agg @ {swk, swv})
    gemmN<2, 3, false, false, 1><<<256, 256, 0, stream>>>(
        agg, nullptr, B_SZ, frags, (int4){5, 6, 0, 0},
        sbk, sbv, nullptr, nullptr,
        (char*)k2, (char*)v2, nullptr, nullptr, 128);

    sem_attn<<<B_SZ / 4, 256, 0, stream>>>(qs, k1, v1, k2, v2, outf);

    // out = relu(ys @ swo + sbo), in place (per-wave rows disjoint; stores
    // depend on all loads through MFMA dataflow)
    gemmN<1, 3, false, false, 1><<<256, 256, 0, stream>>>(
        outf, nullptr, B_SZ, frags, (int4){7, 0, 0, 0},
        sbo, nullptr, nullptr, nullptr,
        (char*)outf, nullptr, nullptr, nullptr, 128);
}

// Round 3
// 316.776 us; speedup vs baseline: 1.6100x; 1.5078x over previous
//
#include <hip/hip_runtime.h>
#include <math.h>

typedef __bf16 bf16_t;
typedef bf16_t bf16x8 __attribute__((ext_vector_type(8)));
typedef float  f32x4  __attribute__((ext_vector_type(4)));
typedef unsigned short u16;

#define B_SZ   16384
#define H_SZ   50
#define NI_SZ  100000
#define SCALE  0.08838834764831845f   /* 1/sqrt(128) */
#define FRAG_W 32768                  /* u16 elems per W (hi 16384 + lo 16384) */

// Logical-k bijection used consistently for A and B frags of
// mfma_f32_16x16x32_bf16:  k = kk*32 + 16*(e>>2) + 4*l4 + (e&3).
// C/D layout (HW): col = lane&15, row = (lane>>4)*4 + reg.

// ---------------------------------------------------------------------------
// Prep: W[k][n] (f32 128x128) -> frag-ready hi/lo bf16; a wave's (kk,nblk)
// B-frag read is 1024 contiguous bytes at ((kk*8+nblk)*64+lane)*8.
// ---------------------------------------------------------------------------
struct WPtrs { const float* p[8]; };

__global__ void prep_frags(WPtrs wp, u16* __restrict__ dst)
{
    int tid = blockIdx.x * 256 + threadIdx.x;      // 8 * 16384 threads
    int w = tid >> 14, idx = tid & 16383;
    int k = idx >> 7, n = idx & 127;
    float v = wp.p[w][idx];
    bf16_t hi = (bf16_t)v;
    bf16_t lo = (bf16_t)(v - (float)hi);
    int kk = k >> 5, k32 = k & 31;
    int e  = ((k32 >> 4) & 1) * 4 + (k32 & 3);
    int l4 = (k32 >> 2) & 3;
    int lane = l4 * 16 + (n & 15);
    int pos = ((kk * 8 + (n >> 4)) * 64 + lane) * 8 + e;
    union { bf16_t b; u16 u; } ch, cl; ch.b = hi; cl.b = lo;
    dst[(size_t)w * FRAG_W + pos]         = ch.u;
    dst[(size_t)w * FRAG_W + 16384 + pos] = cl.u;
}

// ---------------------------------------------------------------------------
// GEMM, latency-optimized: each WAVE owns one unit = (16-row tile, weight w,
// column half).  No inter-wave coupling; grid-stride over units.
// TERMS: 1 = bf16 (item path), 3 = split-bf16 hh+lh+hl (~fp32).
// OUTBF16 path (NSPLIT must be 1): per-wave LDS bounce -> 1KB-contiguous
// wave stores (full-line, no RFO).
// ---------------------------------------------------------------------------
template<int TERMS, bool GATHER, bool OUTBF16, int NWOUT, int NSPLIT>
__global__ __launch_bounds__(256, 4)
void gemmW(const float* __restrict__ A, const int* __restrict__ aidx, int M,
           const u16* __restrict__ frags, int4 widx,
           const float* b0, const float* b1, const float* b2, const float* b3,
           char* o0, char* o1, char* o2, char* o3, int rowStride)
{
    constexpr int SUB  = NWOUT * NSPLIT;
    constexpr int NPER = 8 / NSPLIT;
    __shared__ u16 bounce[OUTBF16 ? 4 * 16 * 136 : 4];
    const int t = threadIdx.x, wave = t >> 6, lane = t & 63;
    const int l15 = lane & 15, l4 = lane >> 4;
    const int totalUnits = (M >> 4) * SUB;

    for (int unit = blockIdx.x * 4 + wave; unit < totalUnits; unit += gridDim.x * 4) {
        const int sub  = unit % SUB;
        const int tile = unit / SUB;
        const int w    = sub / NSPLIT;
        const int half = sub % NSPLIT;
        const int row0 = tile * 16;

        const float* bias = b0; char* out = o0; int wi = widx.x;
        if (NWOUT > 1 && w == 1) { bias = b1; out = o1; wi = widx.y; }
        if (NWOUT > 2 && w == 2) { bias = b2; out = o2; wi = widx.z; }
        if (NWOUT > 3 && w == 3) { bias = b3; out = o3; wi = widx.w; }
        const u16* fh = frags + (size_t)wi * FRAG_W;
        const u16* fl = fh + 16384;

        // ---- A load + repack (16 rows x 128 cols -> 4 k-frags)
        int arow = row0 + l15;
        long src = GATHER ? (long)aidx[arow] : (long)arow;
        const float* Ar = A + src * 128;
        bf16x8 ahi[4], alo[4];
#pragma unroll
        for (int kk = 0; kk < 4; ++kk) {
            f32x4 a0 = *(const f32x4*)(Ar + kk * 32 + 4 * l4);
            f32x4 a1 = *(const f32x4*)(Ar + kk * 32 + 16 + 4 * l4);
#pragma unroll
            for (int e = 0; e < 4; ++e) {
                bf16_t h0 = (bf16_t)a0[e]; ahi[kk][e] = h0;
                bf16_t h1 = (bf16_t)a1[e]; ahi[kk][4 + e] = h1;
                if (TERMS > 1) {
                    alo[kk][e]     = (bf16_t)(a0[e] - (float)h0);
                    alo[kk][4 + e] = (bf16_t)(a1[e] - (float)h1);
                }
            }
        }

        f32x4 acc[NPER];
#pragma unroll
        for (int ni = 0; ni < NPER; ++ni) acc[ni] = (f32x4){0.f, 0.f, 0.f, 0.f};

#pragma unroll
        for (int kk = 0; kk < 4; ++kk)
#pragma unroll
            for (int ni = 0; ni < NPER; ++ni) {
                int n = half * NPER + ni;
                int foff = ((kk * 8 + n) * 64 + lane) * 8;
                bf16x8 bhi = *(const bf16x8*)(fh + foff);
                acc[ni] = __builtin_amdgcn_mfma_f32_16x16x32_bf16(ahi[kk], bhi, acc[ni], 0, 0, 0);
                if (TERMS > 1)
                    acc[ni] = __builtin_amdgcn_mfma_f32_16x16x32_bf16(alo[kk], bhi, acc[ni], 0, 0, 0);
                if (TERMS > 2) {
                    bf16x8 blo = *(const bf16x8*)(fl + foff);
                    acc[ni] = __builtin_amdgcn_mfma_f32_16x16x32_bf16(ahi[kk], blo, acc[ni], 0, 0, 0);
                }
            }

        // ---- epilogue
        if (OUTBF16) {
            u16* bb = (u16*)bounce + wave * (16 * 136);
#pragma unroll
            for (int ni = 0; ni < NPER; ++ni) {
                float bvn = bias[ni * 16 + l15];
#pragma unroll
                for (int r = 0; r < 4; ++r) {
                    float v = acc[ni][r] + bvn;
                    v = v > 0.f ? v : 0.f;
                    union { bf16_t b; u16 u; } c; c.b = (bf16_t)v;
                    bb[(l4 * 4 + r) * 136 + ni * 16 + l15] = c.u;
                }
            }
            __asm__ volatile("s_waitcnt lgkmcnt(0)" ::: "memory");
#pragma unroll
            for (int j = 0; j < 4; ++j) {
                int row = j * 4 + l4;                      // 4 rows/instr, 1KB contiguous
                const u16* sp = bb + row * 136 + l15 * 8;
                char* ob = out + ((size_t)(row0 + row) * rowStride + l15 * 8) * 2;
                *(ulonglong2*)ob = *(const ulonglong2*)sp;
            }
        } else {
#pragma unroll
            for (int ni = 0; ni < NPER; ++ni) {
                int n = half * NPER + ni;
                float bvn = bias[n * 16 + l15];
#pragma unroll
                for (int r = 0; r < 4; ++r) {
                    float v = acc[ni][r] + bvn;
                    v = v > 0.f ? v : 0.f;
                    *(float*)(out + ((size_t)(row0 + l4 * 4 + r) * rowStride + n * 16 + l15) * 4) = v;
                }
            }
        }
    }
}

// ---------------------------------------------------------------------------
// GAT attention, single gather pass.  Wave per batch row: V rows preloaded
// into 50 regs (coalesced 4B/lane), K streamed per-lane, wave softmax,
// in-register PV.
// ---------------------------------------------------------------------------
__global__ __launch_bounds__(256)
void gat_attn(const float* __restrict__ qg, const u16* __restrict__ kt,
              const u16* __restrict__ vt, const int* __restrict__ um,
              float* __restrict__ y)
{
    __shared__ float qsh[4][128];
    const int wave = threadIdx.x >> 6, lane = threadIdx.x & 63;
    const int b = blockIdx.x * 4 + wave;

    float2 q2 = *(const float2*)(qg + (size_t)b * 128 + lane * 2);
    qsh[wave][lane * 2]     = q2.x;
    qsh[wave][lane * 2 + 1] = q2.y;

    int mrow = (lane < H_SZ) ? um[((size_t)b * H_SZ + lane) * 2] : 0;

    unsigned vreg[H_SZ];
#pragma unroll
    for (int h = 0; h < H_SZ; ++h) {
        int vr = __shfl(mrow, h);
        vreg[h] = *(const unsigned*)(vt + (size_t)vr * 128 + lane * 2);
    }
    __syncthreads();

    float s = -1e30f;
    if (lane < H_SZ) {
        const u16* kr = kt + (size_t)mrow * 128;
        float acc = 0.f;
#pragma unroll
        for (int c = 0; c < 4; ++c) {
            bf16x8 kc[4];
#pragma unroll
            for (int j = 0; j < 4; ++j) kc[j] = *(const bf16x8*)(kr + (c * 4 + j) * 8);
#pragma unroll
            for (int j = 0; j < 4; ++j)
#pragma unroll
                for (int e = 0; e < 8; ++e)
                    acc += (float)kc[j][e] * qsh[wave][(c * 4 + j) * 8 + e];
        }
        s = acc * SCALE;
    }
    float m = s;
#pragma unroll
    for (int off = 32; off; off >>= 1) m = fmaxf(m, __shfl_xor(m, off));
    float p = (lane < H_SZ) ? __expf(s - m) : 0.f;
    float sum = p;
#pragma unroll
    for (int off = 32; off; off >>= 1) sum += __shfl_xor(sum, off);
    p /= sum;

    float ax = 0.f, ay = 0.f;
#pragma unroll
    for (int h = 0; h < H_SZ; ++h) {
        float ph = __shfl(p, h);
        unsigned u = vreg[h];
        ax += ph * __uint_as_float(u << 16);
        ay += ph * __uint_as_float(u & 0xffff0000u);
    }
    *(float2*)(y + (size_t)b * 128 + lane * 2) = (float2){ax, ay};
}

// ---------------------------------------------------------------------------
// Semantic attention (2 keys): wave per row, lane owns dims 2l, 2l+1.
// ---------------------------------------------------------------------------
__global__ __launch_bounds__(256)
void sem_attn(const float* __restrict__ qs, const float* __restrict__ k1,
              const float* __restrict__ v1, const float* __restrict__ k2,
              const float* __restrict__ v2, float* __restrict__ out)
{
    const int wave = threadIdx.x >> 6, lane = threadIdx.x & 63;
    const size_t base = ((size_t)(blockIdx.x * 4 + wave)) * 128 + lane * 2;
    float2 q  = *(const float2*)(qs + base);
    float2 a1 = *(const float2*)(k1 + base);
    float2 a2 = *(const float2*)(k2 + base);
    float d1 = q.x * a1.x + q.y * a1.y;
    float d2 = q.x * a2.x + q.y * a2.y;
#pragma unroll
    for (int off = 32; off; off >>= 1) {
        d1 += __shfl_xor(d1, off);
        d2 += __shfl_xor(d2, off);
    }
    float s1 = d1 * SCALE, s2 = d2 * SCALE;
    float m = fmaxf(s1, s2);
    float e1 = __expf(s1 - m), e2 = __expf(s2 - m);
    float inv = 1.f / (e1 + e2);
    float p1 = e1 * inv, p2 = e2 * inv;
    float2 b1 = *(const float2*)(v1 + base);
    float2 b2 = *(const float2*)(v2 + base);
    *(float2*)(out + base) = (float2){p1 * b1.x + p2 * b2.x, p1 * b1.y + p2 * b2.y};
}

// ---------------------------------------------------------------------------
extern "C" void kernel_launch(void* const* d_in, const int* in_sizes, int n_in,
                              void* d_out, int out_size, void* d_ws, size_t ws_size,
                              hipStream_t stream)
{
    const int*   uids       = (const int*)d_in[0];
    const int*   um         = (const int*)d_in[2];
    const float* user_table = (const float*)d_in[3];
    const float* item_table = (const float*)d_in[5];
    const float* gwq = (const float*)d_in[6];  const float* gbq = (const float*)d_in[7];
    const float* gwk = (const float*)d_in[8];  const float* gbk = (const float*)d_in[9];
    const float* gwv = (const float*)d_in[10]; const float* gbv = (const float*)d_in[11];
    const float* gwo = (const float*)d_in[12]; const float* gbo = (const float*)d_in[13];
    const float* swq = (const float*)d_in[14]; const float* sbq = (const float*)d_in[15];
    const float* swk = (const float*)d_in[16]; const float* sbk = (const float*)d_in[17];
    const float* swv = (const float*)d_in[18]; const float* sbv = (const float*)d_in[19];
    const float* swo = (const float*)d_in[20]; const float* sbo = (const float*)d_in[21];

    char* ws = (char*)d_ws;
    u16*   kt    = (u16*)ws;   ws += (size_t)NI_SZ * 128 * 2;     // 25.6 MB
    u16*   vt    = (u16*)ws;   ws += (size_t)NI_SZ * 128 * 2;     // 25.6 MB
    u16*   frags = (u16*)ws;   ws += (size_t)8 * FRAG_W * 2;      // 0.5 MB
    float* qg  = (float*)ws;   ws += (size_t)B_SZ * 128 * 4;
    float* qs  = (float*)ws;   ws += (size_t)B_SZ * 128 * 4;
    float* k1  = (float*)ws;   ws += (size_t)B_SZ * 128 * 4;
    float* v1  = (float*)ws;   ws += (size_t)B_SZ * 128 * 4;
    float* yb  = (float*)ws;   ws += (size_t)B_SZ * 128 * 4;
    float* agg = (float*)ws;   ws += (size_t)B_SZ * 128 * 4;
    // k2/v2/ys reuse regions that are dead by the time they're written
    float* k2 = (float*)kt;
    float* v2 = (float*)vt;
    float* outf = (float*)d_out;

    // W order: 0 gwq, 1 gwk, 2 gwv, 3 gwo, 4 swq, 5 swk, 6 swv, 7 swo
    WPtrs wp; wp.p[0]=gwq; wp.p[1]=gwk; wp.p[2]=gwv; wp.p[3]=gwo;
              wp.p[4]=swq; wp.p[5]=swk; wp.p[6]=swv; wp.p[7]=swo;
    prep_frags<<<512, 256, 0, stream>>>(wp, frags);

    // Item K+V: units = 6250 tiles x 2 W = 12500
    gemmW<1, false, true, 2, 1><<<3125, 256, 0, stream>>>(
        item_table, nullptr, NI_SZ, frags, (int4){1, 2, 0, 0},
        gbk, gbv, nullptr, nullptr,
        (char*)kt, (char*)vt, nullptr, nullptr, 128);

    // Node projections: gat_q, sem_q, sem_k1, sem_v1; units = 1024*4*2 = 8192
    gemmW<3, true, false, 4, 2><<<2048, 256, 0, stream>>>(
        user_table, uids, B_SZ, frags, (int4){0, 4, 5, 6},
        gbq, sbq, sbk, sbv,
        (char*)qg, (char*)qs, (char*)k1, (char*)v1, 128);

    gat_attn<<<B_SZ / 4, 256, 0, stream>>>(qg, kt, vt, um, yb);

    // agg = relu(yb @ gwo + gbo); units = 2048
    gemmW<3, false, false, 1, 2><<<512, 256, 0, stream>>>(
        yb, nullptr, B_SZ, frags, (int4){3, 0, 0, 0},
        gbo, nullptr, nullptr, nullptr,
        (char*)agg, nullptr, nullptr, nullptr, 128);

    // k2, v2 = relu(agg @ {swk, swv}); units = 4096
    gemmW<3, false, false, 2, 2><<<1024, 256, 0, stream>>>(
        agg, nullptr, B_SZ, frags, (int4){5, 6, 0, 0},
        sbk, sbv, nullptr, nullptr,
        (char*)k2, (char*)v2, nullptr, nullptr, 128);

    // ys -> agg (agg dead after k2v2), avoids in-place final GEMM
    sem_attn<<<B_SZ / 4, 256, 0, stream>>>(qs, k1, v1, k2, v2, agg);

    // out = relu(ys @ swo + sbo); units = 2048
    gemmW<3, false, false, 1, 2><<<512, 256, 0, stream>>>(
        agg, nullptr, B_SZ, frags, (int4){7, 0, 0, 0},
        sbo, nullptr, nullptr, nullptr,
        (char*)outf, nullptr, nullptr, nullptr, 128);
}